// Round 14
// baseline (323.422 us; speedup 1.0000x reference)
//
#include <hip/hip_runtime.h>
#include <hip/hip_bf16.h>
#include <stdint.h>

typedef __bf16 bf16;
typedef __bf16 bf16x8 __attribute__((ext_vector_type(8)));
typedef __bf16 bf16x4 __attribute__((ext_vector_type(4)));
typedef float f32x4 __attribute__((ext_vector_type(4)));

#define GLOAD_LDS16(gptr, lptr)                                                        \
  __builtin_amdgcn_global_load_lds((const __attribute__((address_space(1))) void*)(gptr), \
                                   (__attribute__((address_space(3))) void*)(lptr), 16, 0, 0)

// ---------------- weight cast fp32 -> bf16 ----------------
__global__ __launch_bounds__(256) void cast_f2b(const float* __restrict__ in,
                                                bf16* __restrict__ out, int n) {
  int i = (blockIdx.x * 256 + threadIdx.x) * 4;
  if (i >= n) return;
  const float4 v = *(const float4*)(in + i);
  bf16x4 o;
  o[0] = (bf16)v.x; o[1] = (bf16)v.y; o[2] = (bf16)v.z; o[3] = (bf16)v.w;
  *(bf16x4*)(out + i) = o;
}

__global__ __launch_bounds__(256) void zero_k(float* __restrict__ p, int n) {
  int i = blockIdx.x * 256 + threadIdx.x;
  if (i < n) p[i] = 0.f;
}

// ---------------- prep v2: cast+transpose x -> xbT[n][c], 2x2 maxpool -> pxT[m][c]
// Block covers 64 c x 128 n (one h row-pair). float4 global loads; bf16x8
// (16B/lane) stores -> 128B-contiguous write segments (old version wrote 2B/lane).
// grid = (512, NB): bid&31 = h0, bid>>5 = ct (64-c group).
__global__ __launch_bounds__(256) void prep_kernel(const float* __restrict__ x,
                                                   bf16* __restrict__ xbT,
                                                   bf16* __restrict__ pxT) {
  const int b = blockIdx.y;
  x   += (size_t)b * 1024 * 4096;
  xbT += (size_t)b * 4096 * 1024;
  pxT += (size_t)b * 1024 * 1024;
  const int bid = blockIdx.x;
  const int h0 = bid & 31, ct = bid >> 5;
  const int tid = threadIdx.x;
  __shared__ float tile[64][129];
  const float* xs = x + (size_t)(ct * 64) * 4096 + h0 * 128;
#pragma unroll
  for (int e = 0; e < 8; ++e) {
    const int idx = e * 256 + tid;          // 2048 float4 loads
    const int c = idx >> 5, n4 = (idx & 31) * 4;
    *(float4*)&tile[c][n4] = *(const float4*)&xs[(size_t)c * 4096 + n4];
  }
  __syncthreads();
  // xbT: 128 n x 64 c bf16; 8 threads x 16B per n-row -> 128B contiguous
  bf16* xo = xbT + (size_t)(h0 * 128) * 1024 + ct * 64;
#pragma unroll
  for (int e = 0; e < 4; ++e) {
    const int flat = e * 256 + tid;
    const int n = flat >> 3, c8 = (flat & 7) * 8;
    bf16x8 o;
#pragma unroll
    for (int j = 0; j < 8; ++j) o[j] = (bf16)tile[c8 + j][n];
    *(bf16x8*)&xo[(size_t)n * 1024 + c8] = o;
  }
  // pxT: 32 m x 64 c (2x2 maxpool of the row-pair)
  bf16* po = pxT + (size_t)(h0 * 32) * 1024 + ct * 64;
  {
    const int m = tid >> 3, c8 = (tid & 7) * 8;
    bf16x8 o;
#pragma unroll
    for (int j = 0; j < 8; ++j) {
      const int c = c8 + j;
      float v = fmaxf(fmaxf(tile[c][2 * m], tile[c][2 * m + 1]),
                      fmaxf(tile[c][64 + 2 * m], tile[c][64 + 2 * m + 1]));
      o[j] = (bf16)v;
    }
    *(bf16x8*)&po[(size_t)m * 1024 + c8] = o;
  }
}

// ======== 128x256-tile GEMM: C[MxN] = A[MxK] * B[NxK]^T  (R9 schedule) ========
// 8 waves (2M x 4N), per-wave 64x64 output. BK=32, ring-2 LDS (48KB).
// Body T: vmcnt(0) [stage T, 1-deep prefetch] -> s_barrier -> issue stage(T+1)
// -> 8 swizzled ds_read_b128 + 16 MFMA. Write/read hazards separated by the
// barrier (readers' ds_reads drained by compiler lgkm-waits pre-MFMA).
// LDS swizzle: 16B slot = kb ^ ((row>>1)&3), inverse applied on global src.
// EPI: 1 bf16 (acc+bias[col])*scale ; 2 bf16 acc+bias[row] ;
//      4 fp32 acc+bias[row]+resid ;
//      5 bf16 exp(acc) + atomic row-sums into rs_out ; 7 bf16 acc/bias[z*4096+row]
template <int EPI>
__global__ __launch_bounds__(512, 4) void gemm256(
    const bf16* __restrict__ A, long long sA, int lda,
    const bf16* __restrict__ B, long long sB, int ldb,
    void* __restrict__ Cv, long long sC, int ldc, int K,
    const float* __restrict__ bias,
    const float* __restrict__ resid, long long sResid, float scale,
    float* __restrict__ rs_out) {
  const int z = blockIdx.z;
  A += (size_t)z * sA;
  B += (size_t)z * sB;
  const int tid = threadIdx.x;
  const int w = tid >> 6, lane = tid & 63;
  const int r16 = lane & 15, q4 = lane >> 4;
  const int wm = w >> 2, wn = w & 3;
  const long long tileM = (long long)blockIdx.x * 128;
  const long long tileN = (long long)blockIdx.y * 256;

  __shared__ bf16 As[2][4096];  // 16KB: [slot][128 rows][32 k], swizzled 16B lanes
  __shared__ bf16 Bs[2][8192];  // 32KB: [slot][256 rows][32 k]

  f32x4 acc[4][4] = {};

  // staging: thread covers (row = tid>>2, 16B-slot = tid&3); B adds row+128.
  const int srow = tid >> 2;
  const int skb  = (tid & 3) ^ ((srow >> 1) & 3);   // inverse swizzle on source
  const char* Ag = (const char*)A + ((size_t)(tileM + srow) * lda + skb * 8) * 2;
  const char* Bg = (const char*)B + ((size_t)(tileN + srow) * ldb + skb * 8) * 2;
  const size_t b128 = (size_t)128 * ldb * 2;   // ((r+128)>>1)&3 == (r>>1)&3

  auto stage = [&](int T) {  // 3 vm-ops
    const int sl = T & 1;
    GLOAD_LDS16(Ag + (size_t)T * 64, &As[sl][w * 512]);
    GLOAD_LDS16(Bg + (size_t)T * 64, &Bs[sl][w * 512]);
    GLOAD_LDS16(Bg + (size_t)T * 64 + b128, &Bs[sl][4096 + w * 512]);
  };

  stage(0);
  const int NT = K >> 5;

  for (int T = 0; T < NT; ++T) {
    asm volatile("s_waitcnt vmcnt(0)" ::: "memory");  // stage(T) done (own ops)
    __builtin_amdgcn_s_barrier();                     // -> all waves' stage(T) done
    asm volatile("" ::: "memory");
    if (T + 1 < NT) stage(T + 1);                     // slot (T+1)&1: old readers
                                                      // finished before this barrier
    const char* Asl = (const char*)&As[T & 1][0];
    const char* Bsl = (const char*)&Bs[T & 1][0];
    bf16x8 af[4], bf_[4];
#pragma unroll
    for (int mi = 0; mi < 4; ++mi) {
      const int row = wm * 64 + mi * 16 + r16;
      af[mi] = *(const bf16x8*)(Asl + row * 64 + ((q4 ^ ((row >> 1) & 3)) << 4));
    }
#pragma unroll
    for (int ni = 0; ni < 4; ++ni) {
      const int row = wn * 64 + ni * 16 + r16;
      bf_[ni] = *(const bf16x8*)(Bsl + row * 64 + ((q4 ^ ((row >> 1) & 3)) << 4));
    }
    __builtin_amdgcn_s_setprio(1);
#pragma unroll
    for (int mi = 0; mi < 4; ++mi)
#pragma unroll
      for (int ni = 0; ni < 4; ++ni)
        acc[mi][ni] = __builtin_amdgcn_mfma_f32_16x16x32_bf16(af[mi], bf_[ni], acc[mi][ni], 0, 0, 0);
    __builtin_amdgcn_s_setprio(0);
  }

  if constexpr (EPI == 4) {
    float* C = (float*)Cv + (size_t)z * sC;
    const float* rz = resid + (size_t)z * sResid;
#pragma unroll
    for (int a = 0; a < 4; ++a) {
      const int row0 = (int)tileM + wm * 64 + a * 16 + q4 * 4;
#pragma unroll
      for (int ni = 0; ni < 4; ++ni) {
        const int col = (int)tileN + wn * 64 + ni * 16 + r16;
#pragma unroll
        for (int r = 0; r < 4; ++r)
          C[(size_t)(row0 + r) * ldc + col] =
              acc[a][ni][r] + bias[row0 + r] + rz[(size_t)(row0 + r) * ldc + col];
      }
    }
  } else if constexpr (EPI == 5) {
    bf16* C = (bf16*)Cv + (size_t)z * sC;
    float* rsp = rs_out + (size_t)z * 4096;
#pragma unroll
    for (int a = 0; a < 4; ++a) {
      const int row0 = (int)tileM + wm * 64 + a * 16 + q4 * 4;
      float psum[4] = {0.f, 0.f, 0.f, 0.f};
#pragma unroll
      for (int ni = 0; ni < 4; ++ni) {
        const int col = (int)tileN + wn * 64 + ni * 16 + r16;
#pragma unroll
        for (int r = 0; r < 4; ++r) {
          float e = __expf(acc[a][ni][r]);
          psum[r] += e;
          C[(size_t)(row0 + r) * ldc + col] = (bf16)e;
        }
      }
#pragma unroll
      for (int r = 0; r < 4; ++r) {
        float v = psum[r];
        v += __shfl_xor(v, 1);
        v += __shfl_xor(v, 2);
        v += __shfl_xor(v, 4);
        v += __shfl_xor(v, 8);
        if (r16 == 0) atomicAdd(&rsp[row0 + r], v);
      }
    }
  } else if constexpr (EPI == 7) {
    bf16* C = (bf16*)Cv + (size_t)z * sC;
    const float* rsp = bias + (size_t)z * 4096;
#pragma unroll
    for (int a = 0; a < 4; ++a) {
      const int row0 = (int)tileM + wm * 64 + a * 16 + q4 * 4;
      float inv[4];
#pragma unroll
      for (int r = 0; r < 4; ++r) inv[r] = 1.0f / rsp[row0 + r];
#pragma unroll
      for (int ni = 0; ni < 4; ++ni) {
        const int col = (int)tileN + wn * 64 + ni * 16 + r16;
#pragma unroll
        for (int r = 0; r < 4; ++r)
          C[(size_t)(row0 + r) * ldc + col] = (bf16)(acc[a][ni][r] * inv[r]);
      }
    }
  } else if constexpr (EPI == 2) {
    bf16* C = (bf16*)Cv + (size_t)z * sC;
#pragma unroll
    for (int a = 0; a < 4; ++a) {
      const int row0 = (int)tileM + wm * 64 + a * 16 + q4 * 4;
#pragma unroll
      for (int ni = 0; ni < 4; ++ni) {
        const int col = (int)tileN + wn * 64 + ni * 16 + r16;
#pragma unroll
        for (int r = 0; r < 4; ++r)
          C[(size_t)(row0 + r) * ldc + col] = (bf16)(acc[a][ni][r] + bias[row0 + r]);
      }
    }
  } else {  // EPI == 1
    bf16* C = (bf16*)Cv + (size_t)z * sC;
#pragma unroll
    for (int a = 0; a < 4; ++a) {
      const int row0 = (int)tileM + wm * 64 + a * 16 + q4 * 4;
#pragma unroll
      for (int ni = 0; ni < 4; ++ni) {
        const int col = (int)tileN + wn * 64 + ni * 16 + r16;
        const float badd = bias[col];
#pragma unroll
        for (int r = 0; r < 4; ++r)
          C[(size_t)(row0 + r) * ldc + col] = (bf16)((acc[a][ni][r] + badd) * scale);
      }
    }
  }
}

// ---------------- launch ----------------
extern "C" void kernel_launch(void* const* d_in, const int* in_sizes, int n_in,
                              void* d_out, int out_size, void* d_ws, size_t ws_size,
                              hipStream_t stream) {
  const float* x  = (const float*)d_in[0];
  const float* Wt = (const float*)d_in[1];
  const float* bt = (const float*)d_in[2];
  const float* Wp = (const float*)d_in[3];
  const float* bp = (const float*)d_in[4];
  const float* Wg = (const float*)d_in[5];
  const float* bg = (const float*)d_in[6];
  const float* Wo = (const float*)d_in[7];
  const float* bo = (const float*)d_in[8];
  float* out = (float*)d_out;

  const size_t MB = 1024ull * 1024ull;
  char* ws = (char*)d_ws;
  bf16* WtB = (bf16*)(ws + 0 * MB);
  bf16* WpB = (bf16*)(ws + 1 * MB);
  bf16* WgB = (bf16*)(ws + 2 * MB);
  bf16* WoB = (bf16*)(ws + 3 * MB);

  cast_f2b<<<512, 256, 0, stream>>>(Wt, WtB, 512 * 1024);
  cast_f2b<<<512, 256, 0, stream>>>(Wp, WpB, 512 * 1024);
  cast_f2b<<<512, 256, 0, stream>>>(Wg, WgB, 512 * 1024);
  cast_f2b<<<512, 256, 0, stream>>>(Wo, WoB, 1024 * 512);

  const float SCALE = 0.044194173824159216f;  // 512^-0.5, folded into theta

  auto run_g6 = [&](int nb, int b0, bf16* tT) {
    gemm256<4><<<dim3(8, 16, nb), 512, 0, stream>>>(WoB, 0, 512, tT, 4096ll * 512, 512,
                                                    out + (size_t)b0 * 1024 * 4096,
                                                    1024ll * 4096, 4096, 512,
                                                    bo, x + (size_t)b0 * 1024 * 4096,
                                                    1024ll * 4096, 1.f, nullptr);
  };

  if (ws_size >= 164 * MB) {
    bf16* pxT    = (bf16*)(ws + 4 * MB);     // 16MB
    bf16* phiT   = (bf16*)(ws + 20 * MB);    // 8MB
    bf16* g      = (bf16*)(ws + 28 * MB);    // 8MB
    bf16* thetaT = (bf16*)(ws + 36 * MB);    // 32MB
    bf16* tT     = (bf16*)(ws + 68 * MB);    // 32MB
    bf16* xbT    = (bf16*)(ws + 100 * MB);   // 64MB (staging only; no aliasing)
    bf16*  Pt   = (bf16*)d_out;                       // 64MB scratch in d_out
    float* rsum = (float*)((char*)d_out + 80 * MB);   // 128KB scratch in d_out

    prep_kernel<<<dim3(512, 8), 256, 0, stream>>>(x, xbT, pxT);
    gemm256<1><<<dim3(32, 2, 8), 512, 0, stream>>>(xbT, 4096ll * 1024, 1024, WtB, 0, 1024,
                                                   thetaT, 4096ll * 512, 512, 1024,
                                                   bt, nullptr, 0, SCALE, nullptr);
    gemm256<1><<<dim3(8, 2, 8), 512, 0, stream>>>(pxT, 1024ll * 1024, 1024, WpB, 0, 1024,
                                                  phiT, 1024ll * 512, 512, 1024,
                                                  bp, nullptr, 0, 1.f, nullptr);
    gemm256<2><<<dim3(4, 4, 8), 512, 0, stream>>>(WgB, 0, 1024, pxT, 1024ll * 1024, 1024,
                                                  g, 512ll * 1024, 1024, 1024,
                                                  bg, nullptr, 0, 1.f, nullptr);
    zero_k<<<128, 256, 0, stream>>>(rsum, 32768);
    gemm256<5><<<dim3(32, 4, 8), 512, 0, stream>>>(thetaT, 4096ll * 512, 512,
                                                   phiT, 1024ll * 512, 512,
                                                   Pt, 4096ll * 1024, 1024, 512,
                                                   nullptr, nullptr, 0, 1.f, rsum);
    gemm256<7><<<dim3(32, 2, 8), 512, 0, stream>>>(Pt, 4096ll * 1024, 1024,
                                                   g, 512ll * 1024, 1024,
                                                   tT, 4096ll * 512, 512, 1024,
                                                   rsum, nullptr, 0, 1.f, nullptr);
    run_g6(8, 0, tT);
  } else if (ws_size >= 108 * MB) {
    bf16* pxT    = (bf16*)(ws + 4 * MB);
    bf16* phiT   = (bf16*)(ws + 20 * MB);
    bf16* g      = (bf16*)(ws + 28 * MB);
    bf16* thetaT = (bf16*)(ws + 36 * MB);
    bf16* tT     = (bf16*)(ws + 68 * MB);
    bf16* xbT    = (bf16*)(ws + 100 * MB);   // 8MB per-batch staging
    float* rsum = (float*)((char*)d_out + 80 * MB);
    for (int b = 0; b < 8; ++b) {
      prep_kernel<<<dim3(512, 1), 256, 0, stream>>>(x + (size_t)b * 1024 * 4096, xbT,
                                                    pxT + (size_t)b * 1024 * 1024);
      gemm256<1><<<dim3(32, 2, 1), 512, 0, stream>>>(xbT, 0, 1024, WtB, 0, 1024,
                                                     thetaT + (size_t)b * 4096 * 512, 0, 512,
                                                     1024, bt, nullptr, 0, SCALE, nullptr);
    }
    gemm256<1><<<dim3(8, 2, 8), 512, 0, stream>>>(pxT, 1024ll * 1024, 1024, WpB, 0, 1024,
                                                  phiT, 1024ll * 512, 512, 1024,
                                                  bp, nullptr, 0, 1.f, nullptr);
    gemm256<2><<<dim3(4, 4, 8), 512, 0, stream>>>(WgB, 0, 1024, pxT, 1024ll * 1024, 1024,
                                                  g, 512ll * 1024, 1024, 1024,
                                                  bg, nullptr, 0, 1.f, nullptr);
    for (int b = 0; b < 8; ++b) {
      bf16* Ptb = (bf16*)d_out + (size_t)b * 4096 * 1024;
      zero_k<<<16, 256, 0, stream>>>(rsum + (size_t)b * 4096, 4096);
      gemm256<5><<<dim3(32, 4, 1), 512, 0, stream>>>(thetaT + (size_t)b * 4096 * 512, 0, 512,
                                                     phiT + (size_t)b * 1024 * 512, 0, 512,
                                                     Ptb, 0, 1024, 512,
                                                     nullptr, nullptr, 0, 1.f,
                                                     rsum + (size_t)b * 4096);
      gemm256<7><<<dim3(32, 2, 1), 512, 0, stream>>>(Ptb, 0, 1024,
                                                     g + (size_t)b * 512 * 1024, 0, 1024,
                                                     tT + (size_t)b * 4096 * 512, 0, 512, 1024,
                                                     rsum + (size_t)b * 4096, nullptr, 0, 1.f,
                                                     nullptr);
    }
    run_g6(8, 0, tT);
  } else {
    float* rsum  = (float*)(ws + 4 * MB);    // 16KB
    bf16* pxT    = (bf16*)(ws + 5 * MB);     // 2MB
    bf16* phiT   = (bf16*)(ws + 7 * MB);     // 1MB
    bf16* g      = (bf16*)(ws + 8 * MB);     // 1MB
    bf16* thetaT = (bf16*)(ws + 9 * MB);     // 4MB
    bf16* tT     = (bf16*)(ws + 13 * MB);    // 4MB
    bf16* Pt     = (bf16*)(ws + 17 * MB);    // 8MB
    bf16* xbT    = (bf16*)(ws + 25 * MB);    // 8MB -> 33MB total
    for (int b = 0; b < 8; ++b) {
      prep_kernel<<<dim3(512, 1), 256, 0, stream>>>(x + (size_t)b * 1024 * 4096, xbT, pxT);
      gemm256<1><<<dim3(32, 2, 1), 512, 0, stream>>>(xbT, 0, 1024, WtB, 0, 1024,
                                                     thetaT, 0, 512, 1024,
                                                     bt, nullptr, 0, SCALE, nullptr);
      gemm256<1><<<dim3(8, 2, 1), 512, 0, stream>>>(pxT, 0, 1024, WpB, 0, 1024,
                                                    phiT, 0, 512, 1024,
                                                    bp, nullptr, 0, 1.f, nullptr);
      gemm256<2><<<dim3(4, 4, 1), 512, 0, stream>>>(WgB, 0, 1024, pxT, 0, 1024,
                                                    g, 0, 1024, 1024,
                                                    bg, nullptr, 0, 1.f, nullptr);
      zero_k<<<16, 256, 0, stream>>>(rsum, 4096);
      gemm256<5><<<dim3(32, 4, 1), 512, 0, stream>>>(thetaT, 0, 512, phiT, 0, 512,
                                                     Pt, 0, 1024, 512,
                                                     nullptr, nullptr, 0, 1.f, rsum);
      gemm256<7><<<dim3(32, 2, 1), 512, 0, stream>>>(Pt, 0, 1024, g, 0, 1024,
                                                     tT, 0, 512, 1024,
                                                     rsum, nullptr, 0, 1.f, nullptr);
      run_g6(1, b, tT);
    }
  }
}

// Round 15
// 320.890 us; speedup vs baseline: 1.0079x; 1.0079x over previous
//
#include <hip/hip_runtime.h>
#include <hip/hip_bf16.h>
#include <stdint.h>

typedef __bf16 bf16;
typedef __bf16 bf16x8 __attribute__((ext_vector_type(8)));
typedef __bf16 bf16x4 __attribute__((ext_vector_type(4)));
typedef float f32x4 __attribute__((ext_vector_type(4)));

#define GLOAD_LDS16(gptr, lptr)                                                        \
  __builtin_amdgcn_global_load_lds((const __attribute__((address_space(1))) void*)(gptr), \
                                   (__attribute__((address_space(3))) void*)(lptr), 16, 0, 0)

// ---------------- weight cast fp32 -> bf16 ----------------
__global__ __launch_bounds__(256) void cast_f2b(const float* __restrict__ in,
                                                bf16* __restrict__ out, int n) {
  int i = (blockIdx.x * 256 + threadIdx.x) * 4;
  if (i >= n) return;
  const float4 v = *(const float4*)(in + i);
  bf16x4 o;
  o[0] = (bf16)v.x; o[1] = (bf16)v.y; o[2] = (bf16)v.z; o[3] = (bf16)v.w;
  *(bf16x4*)(out + i) = o;
}

__global__ __launch_bounds__(256) void zero_k(float* __restrict__ p, int n) {
  int i = blockIdx.x * 256 + threadIdx.x;
  if (i < n) p[i] = 0.f;
}

// concat [bp(512); bg(512)] -> o[1024]
__global__ __launch_bounds__(256) void concat512(const float* __restrict__ a,
                                                 const float* __restrict__ b,
                                                 float* __restrict__ o) {
  int i = blockIdx.x * 256 + threadIdx.x;
  if (i < 512) o[i] = a[i];
  else if (i < 1024) o[i] = b[i - 512];
}

// ---------------- prep v2: cast+transpose x -> xbT[n][c], 2x2 maxpool -> pxT[m][c]
__global__ __launch_bounds__(256) void prep_kernel(const float* __restrict__ x,
                                                   bf16* __restrict__ xbT,
                                                   bf16* __restrict__ pxT) {
  const int b = blockIdx.y;
  x   += (size_t)b * 1024 * 4096;
  xbT += (size_t)b * 4096 * 1024;
  pxT += (size_t)b * 1024 * 1024;
  const int bid = blockIdx.x;
  const int h0 = bid & 31, ct = bid >> 5;
  const int tid = threadIdx.x;
  __shared__ float tile[64][129];
  const float* xs = x + (size_t)(ct * 64) * 4096 + h0 * 128;
#pragma unroll
  for (int e = 0; e < 8; ++e) {
    const int idx = e * 256 + tid;
    const int c = idx >> 5, n4 = (idx & 31) * 4;
    *(float4*)&tile[c][n4] = *(const float4*)&xs[(size_t)c * 4096 + n4];
  }
  __syncthreads();
  bf16* xo = xbT + (size_t)(h0 * 128) * 1024 + ct * 64;
#pragma unroll
  for (int e = 0; e < 4; ++e) {
    const int flat = e * 256 + tid;
    const int n = flat >> 3, c8 = (flat & 7) * 8;
    bf16x8 o;
#pragma unroll
    for (int j = 0; j < 8; ++j) o[j] = (bf16)tile[c8 + j][n];
    *(bf16x8*)&xo[(size_t)n * 1024 + c8] = o;
  }
  bf16* po = pxT + (size_t)(h0 * 32) * 1024 + ct * 64;
  {
    const int m = tid >> 3, c8 = (tid & 7) * 8;
    bf16x8 o;
#pragma unroll
    for (int j = 0; j < 8; ++j) {
      const int c = c8 + j;
      float v = fmaxf(fmaxf(tile[c][2 * m], tile[c][2 * m + 1]),
                      fmaxf(tile[c][64 + 2 * m], tile[c][64 + 2 * m + 1]));
      o[j] = (bf16)v;
    }
    *(bf16x8*)&po[(size_t)m * 1024 + c8] = o;
  }
}

// ======== 128x256-tile GEMM: C[MxN] = A[MxK] * B[NxK]^T  (R9 schedule) ========
// EPI: 0 plain bf16 ; 1 bf16 (acc+bias[col])*scale ; 2 bf16 acc+bias[row] ;
//      4 fp32 acc+bias[row]+resid ; 5 bf16 exp(acc) + atomic row-sums rs_out ;
//      7 bf16 acc/bias[z*4096+row] ;
//      8 fp32 acc/rs_out[z*4096+col] + bias[row] + resid   [fused PV+out]
template <int EPI>
__global__ __launch_bounds__(512, 4) void gemm256(
    const bf16* __restrict__ A, long long sA, int lda,
    const bf16* __restrict__ B, long long sB, int ldb,
    void* __restrict__ Cv, long long sC, int ldc, int K,
    const float* __restrict__ bias,
    const float* __restrict__ resid, long long sResid, float scale,
    float* __restrict__ rs_out) {
  const int z = blockIdx.z;
  A += (size_t)z * sA;
  B += (size_t)z * sB;
  const int tid = threadIdx.x;
  const int w = tid >> 6, lane = tid & 63;
  const int r16 = lane & 15, q4 = lane >> 4;
  const int wm = w >> 2, wn = w & 3;
  const long long tileM = (long long)blockIdx.x * 128;
  const long long tileN = (long long)blockIdx.y * 256;

  __shared__ bf16 As[2][4096];
  __shared__ bf16 Bs[2][8192];

  f32x4 acc[4][4] = {};

  const int srow = tid >> 2;
  const int skb  = (tid & 3) ^ ((srow >> 1) & 3);   // inverse swizzle on source
  const char* Ag = (const char*)A + ((size_t)(tileM + srow) * lda + skb * 8) * 2;
  const char* Bg = (const char*)B + ((size_t)(tileN + srow) * ldb + skb * 8) * 2;
  const size_t b128 = (size_t)128 * ldb * 2;

  auto stage = [&](int T) {
    const int sl = T & 1;
    GLOAD_LDS16(Ag + (size_t)T * 64, &As[sl][w * 512]);
    GLOAD_LDS16(Bg + (size_t)T * 64, &Bs[sl][w * 512]);
    GLOAD_LDS16(Bg + (size_t)T * 64 + b128, &Bs[sl][4096 + w * 512]);
  };

  stage(0);
  const int NT = K >> 5;

  for (int T = 0; T < NT; ++T) {
    asm volatile("s_waitcnt vmcnt(0)" ::: "memory");
    __builtin_amdgcn_s_barrier();
    asm volatile("" ::: "memory");
    if (T + 1 < NT) stage(T + 1);

    const char* Asl = (const char*)&As[T & 1][0];
    const char* Bsl = (const char*)&Bs[T & 1][0];
    bf16x8 af[4], bf_[4];
#pragma unroll
    for (int mi = 0; mi < 4; ++mi) {
      const int row = wm * 64 + mi * 16 + r16;
      af[mi] = *(const bf16x8*)(Asl + row * 64 + ((q4 ^ ((row >> 1) & 3)) << 4));
    }
#pragma unroll
    for (int ni = 0; ni < 4; ++ni) {
      const int row = wn * 64 + ni * 16 + r16;
      bf_[ni] = *(const bf16x8*)(Bsl + row * 64 + ((q4 ^ ((row >> 1) & 3)) << 4));
    }
    __builtin_amdgcn_s_setprio(1);
#pragma unroll
    for (int mi = 0; mi < 4; ++mi)
#pragma unroll
      for (int ni = 0; ni < 4; ++ni)
        acc[mi][ni] = __builtin_amdgcn_mfma_f32_16x16x32_bf16(af[mi], bf_[ni], acc[mi][ni], 0, 0, 0);
    __builtin_amdgcn_s_setprio(0);
  }

  if constexpr (EPI == 4) {
    float* C = (float*)Cv + (size_t)z * sC;
    const float* rz = resid + (size_t)z * sResid;
#pragma unroll
    for (int a = 0; a < 4; ++a) {
      const int row0 = (int)tileM + wm * 64 + a * 16 + q4 * 4;
#pragma unroll
      for (int ni = 0; ni < 4; ++ni) {
        const int col = (int)tileN + wn * 64 + ni * 16 + r16;
#pragma unroll
        for (int r = 0; r < 4; ++r)
          C[(size_t)(row0 + r) * ldc + col] =
              acc[a][ni][r] + bias[row0 + r] + rz[(size_t)(row0 + r) * ldc + col];
      }
    }
  } else if constexpr (EPI == 8) {
    float* C = (float*)Cv + (size_t)z * sC;
    const float* rz = resid + (size_t)z * sResid;
    const float* rsp = rs_out + (size_t)z * 4096;
#pragma unroll
    for (int a = 0; a < 4; ++a) {
      const int row0 = (int)tileM + wm * 64 + a * 16 + q4 * 4;
      float bv[4];
#pragma unroll
      for (int r = 0; r < 4; ++r) bv[r] = bias[row0 + r];
#pragma unroll
      for (int ni = 0; ni < 4; ++ni) {
        const int col = (int)tileN + wn * 64 + ni * 16 + r16;
        const float cinv = 1.0f / rsp[col];
#pragma unroll
        for (int r = 0; r < 4; ++r)
          C[(size_t)(row0 + r) * ldc + col] =
              acc[a][ni][r] * cinv + bv[r] + rz[(size_t)(row0 + r) * ldc + col];
      }
    }
  } else if constexpr (EPI == 5) {
    bf16* C = (bf16*)Cv + (size_t)z * sC;
    float* rsp = rs_out + (size_t)z * 4096;
#pragma unroll
    for (int a = 0; a < 4; ++a) {
      const int row0 = (int)tileM + wm * 64 + a * 16 + q4 * 4;
      float psum[4] = {0.f, 0.f, 0.f, 0.f};
#pragma unroll
      for (int ni = 0; ni < 4; ++ni) {
        const int col = (int)tileN + wn * 64 + ni * 16 + r16;
#pragma unroll
        for (int r = 0; r < 4; ++r) {
          float e = __expf(acc[a][ni][r]);
          psum[r] += e;
          C[(size_t)(row0 + r) * ldc + col] = (bf16)e;
        }
      }
#pragma unroll
      for (int r = 0; r < 4; ++r) {
        float v = psum[r];
        v += __shfl_xor(v, 1);
        v += __shfl_xor(v, 2);
        v += __shfl_xor(v, 4);
        v += __shfl_xor(v, 8);
        if (r16 == 0) atomicAdd(&rsp[row0 + r], v);
      }
    }
  } else if constexpr (EPI == 7) {
    bf16* C = (bf16*)Cv + (size_t)z * sC;
    const float* rsp = bias + (size_t)z * 4096;
#pragma unroll
    for (int a = 0; a < 4; ++a) {
      const int row0 = (int)tileM + wm * 64 + a * 16 + q4 * 4;
      float inv[4];
#pragma unroll
      for (int r = 0; r < 4; ++r) inv[r] = 1.0f / rsp[row0 + r];
#pragma unroll
      for (int ni = 0; ni < 4; ++ni) {
        const int col = (int)tileN + wn * 64 + ni * 16 + r16;
#pragma unroll
        for (int r = 0; r < 4; ++r)
          C[(size_t)(row0 + r) * ldc + col] = (bf16)(acc[a][ni][r] * inv[r]);
      }
    }
  } else if constexpr (EPI == 2) {
    bf16* C = (bf16*)Cv + (size_t)z * sC;
#pragma unroll
    for (int a = 0; a < 4; ++a) {
      const int row0 = (int)tileM + wm * 64 + a * 16 + q4 * 4;
#pragma unroll
      for (int ni = 0; ni < 4; ++ni) {
        const int col = (int)tileN + wn * 64 + ni * 16 + r16;
#pragma unroll
        for (int r = 0; r < 4; ++r)
          C[(size_t)(row0 + r) * ldc + col] = (bf16)(acc[a][ni][r] + bias[row0 + r]);
      }
    }
  } else if constexpr (EPI == 0) {
    bf16* C = (bf16*)Cv + (size_t)z * sC;
#pragma unroll
    for (int a = 0; a < 4; ++a) {
      const int row0 = (int)tileM + wm * 64 + a * 16 + q4 * 4;
#pragma unroll
      for (int ni = 0; ni < 4; ++ni) {
        const int col = (int)tileN + wn * 64 + ni * 16 + r16;
#pragma unroll
        for (int r = 0; r < 4; ++r)
          C[(size_t)(row0 + r) * ldc + col] = (bf16)acc[a][ni][r];
      }
    }
  } else {  // EPI == 1
    bf16* C = (bf16*)Cv + (size_t)z * sC;
#pragma unroll
    for (int a = 0; a < 4; ++a) {
      const int row0 = (int)tileM + wm * 64 + a * 16 + q4 * 4;
#pragma unroll
      for (int ni = 0; ni < 4; ++ni) {
        const int col = (int)tileN + wn * 64 + ni * 16 + r16;
        const float badd = bias[col];
#pragma unroll
        for (int r = 0; r < 4; ++r)
          C[(size_t)(row0 + r) * ldc + col] = (bf16)((acc[a][ni][r] + badd) * scale);
      }
    }
  }
}

// ---------------- launch ----------------
extern "C" void kernel_launch(void* const* d_in, const int* in_sizes, int n_in,
                              void* d_out, int out_size, void* d_ws, size_t ws_size,
                              hipStream_t stream) {
  const float* x  = (const float*)d_in[0];
  const float* Wt = (const float*)d_in[1];
  const float* bt = (const float*)d_in[2];
  const float* Wp = (const float*)d_in[3];
  const float* bp = (const float*)d_in[4];
  const float* Wg = (const float*)d_in[5];
  const float* bg = (const float*)d_in[6];
  const float* Wo = (const float*)d_in[7];
  const float* bo = (const float*)d_in[8];
  float* out = (float*)d_out;

  const size_t MB = 1024ull * 1024ull;
  char* ws = (char*)d_ws;
  bf16* WtB  = (bf16*)(ws + 0 * MB);            // 1MB
  bf16* WoB  = (bf16*)(ws + 1 * MB);            // 1MB
  bf16* WpgB = (bf16*)(ws + 2 * MB);            // 2MB: rows 0-511 Wp, 512-1023 Wg

  cast_f2b<<<512, 256, 0, stream>>>(Wt, WtB, 512 * 1024);
  cast_f2b<<<512, 256, 0, stream>>>(Wo, WoB, 1024 * 512);
  cast_f2b<<<512, 256, 0, stream>>>(Wp, WpgB, 512 * 1024);
  cast_f2b<<<512, 256, 0, stream>>>(Wg, WpgB + 512 * 1024, 512 * 1024);

  const float SCALE = 0.044194173824159216f;  // 512^-0.5, folded into theta

  if (ws_size >= 164 * MB) {
    // ---- fused pipeline: pg = [phi|gT]; W2 = Wo.gT^T; out = (W2.P^T)/rs + b + x
    float* bias_pg = (float*)(ws + 4 * MB);           // 4KB
    float* rsum    = (float*)(ws + 4 * MB + 65536);   // 128KB
    bf16* pxT    = (bf16*)(ws + 5 * MB);              // 16MB
    bf16* pg     = (bf16*)(ws + 21 * MB);             // 16MB [z][m][d2=1024]
    bf16* thetaT = (bf16*)(ws + 37 * MB);             // 32MB
    bf16* W2     = (bf16*)(ws + 69 * MB);             // 16MB [z][o][m]
    bf16* xbT    = (bf16*)(ws + 100 * MB);            // 64MB
    bf16* Pt     = xbT;                               // xbT dead after G1 (sequential reuse)

    concat512<<<4, 256, 0, stream>>>(bp, bg, bias_pg);
    prep_kernel<<<dim3(512, 8), 256, 0, stream>>>(x, xbT, pxT);
    // G1: thetaT = xbT . Wt^T, scale folded
    gemm256<1><<<dim3(32, 2, 8), 512, 0, stream>>>(xbT, 4096ll * 1024, 1024, WtB, 0, 1024,
                                                   thetaT, 4096ll * 512, 512, 1024,
                                                   bt, nullptr, 0, SCALE, nullptr);
    // pg[m][d2] = pxT . Wpg^T + bias_pg   (phi = pg[:, :512], gT = pg[:, 512:])
    gemm256<1><<<dim3(8, 4, 8), 512, 0, stream>>>(pxT, 1024ll * 1024, 1024, WpgB, 0, 1024,
                                                  pg, 1024ll * 1024, 1024, 1024,
                                                  bias_pg, nullptr, 0, 1.f, nullptr);
    // W2[o][m] = Wo . gT^T
    gemm256<0><<<dim3(8, 4, 8), 512, 0, stream>>>(WoB, 0, 512, pg + 512, 1024ll * 1024, 1024,
                                                  W2, 1024ll * 1024, 1024, 512,
                                                  nullptr, nullptr, 0, 1.f, nullptr);
    zero_k<<<128, 256, 0, stream>>>(rsum, 32768);
    // G4': P~ = exp(thetaT . phi^T) + row-sums
    gemm256<5><<<dim3(32, 4, 8), 512, 0, stream>>>(thetaT, 4096ll * 512, 512,
                                                   pg, 1024ll * 1024, 1024,
                                                   Pt, 4096ll * 1024, 1024, 512,
                                                   nullptr, nullptr, 0, 1.f, rsum);
    // G6': out[o][n] = (W2 . P~^T)/rs[n] + bo[o] + x[o][n]
    gemm256<8><<<dim3(8, 16, 8), 512, 0, stream>>>(W2, 1024ll * 1024, 1024,
                                                   Pt, 4096ll * 1024, 1024,
                                                   out, 1024ll * 4096, 4096, 1024,
                                                   bo, x, 1024ll * 4096, 1.f, rsum);
  } else if (ws_size >= 108 * MB) {
    // ---- R14 split pipeline (proven) ----
    bf16* WpB = WpgB;
    bf16* WgB = WpgB + 512 * 1024;
    bf16* pxT    = (bf16*)(ws + 4 * MB);
    bf16* phiT   = (bf16*)(ws + 20 * MB);
    bf16* g      = (bf16*)(ws + 28 * MB);
    bf16* thetaT = (bf16*)(ws + 36 * MB);
    bf16* tT     = (bf16*)(ws + 68 * MB);
    bf16* xbT    = (bf16*)(ws + 100 * MB);   // 8MB per-batch staging
    float* rsum = (float*)((char*)d_out + 80 * MB);
    for (int b = 0; b < 8; ++b) {
      prep_kernel<<<dim3(512, 1), 256, 0, stream>>>(x + (size_t)b * 1024 * 4096, xbT,
                                                    pxT + (size_t)b * 1024 * 1024);
      gemm256<1><<<dim3(32, 2, 1), 512, 0, stream>>>(xbT, 0, 1024, WtB, 0, 1024,
                                                     thetaT + (size_t)b * 4096 * 512, 0, 512,
                                                     1024, bt, nullptr, 0, SCALE, nullptr);
    }
    gemm256<1><<<dim3(8, 2, 8), 512, 0, stream>>>(pxT, 1024ll * 1024, 1024, WpB, 0, 1024,
                                                  phiT, 1024ll * 512, 512, 1024,
                                                  bp, nullptr, 0, 1.f, nullptr);
    gemm256<2><<<dim3(4, 4, 8), 512, 0, stream>>>(WgB, 0, 1024, pxT, 1024ll * 1024, 1024,
                                                  g, 512ll * 1024, 1024, 1024,
                                                  bg, nullptr, 0, 1.f, nullptr);
    for (int b = 0; b < 8; ++b) {
      bf16* Ptb = (bf16*)d_out + (size_t)b * 4096 * 1024;
      zero_k<<<16, 256, 0, stream>>>(rsum + (size_t)b * 4096, 4096);
      gemm256<5><<<dim3(32, 4, 1), 512, 0, stream>>>(thetaT + (size_t)b * 4096 * 512, 0, 512,
                                                     phiT + (size_t)b * 1024 * 512, 0, 512,
                                                     Ptb, 0, 1024, 512,
                                                     nullptr, nullptr, 0, 1.f,
                                                     rsum + (size_t)b * 4096);
      gemm256<7><<<dim3(32, 2, 1), 512, 0, stream>>>(Ptb, 0, 1024,
                                                     g + (size_t)b * 512 * 1024, 0, 1024,
                                                     tT + (size_t)b * 4096 * 512, 0, 512, 1024,
                                                     rsum + (size_t)b * 4096, nullptr, 0, 1.f,
                                                     nullptr);
    }
    gemm256<4><<<dim3(8, 16, 8), 512, 0, stream>>>(WoB, 0, 512, tT, 4096ll * 512, 512,
                                                   out, 1024ll * 4096, 4096, 512,
                                                   bo, x, 1024ll * 4096, 1.f, nullptr);
  } else {
    // ---- per-batch minimal-ws pipeline ----
    bf16* WpB = WpgB;
    bf16* WgB = WpgB + 512 * 1024;
    float* rsum  = (float*)(ws + 4 * MB);    // 16KB
    bf16* pxT    = (bf16*)(ws + 5 * MB);     // 2MB
    bf16* phiT   = (bf16*)(ws + 7 * MB);     // 1MB
    bf16* g      = (bf16*)(ws + 8 * MB);     // 1MB
    bf16* thetaT = (bf16*)(ws + 9 * MB);     // 4MB
    bf16* tT     = (bf16*)(ws + 13 * MB);    // 4MB
    bf16* Pt     = (bf16*)(ws + 17 * MB);    // 8MB
    bf16* xbT    = (bf16*)(ws + 25 * MB);    // 8MB
    for (int b = 0; b < 8; ++b) {
      prep_kernel<<<dim3(512, 1), 256, 0, stream>>>(x + (size_t)b * 1024 * 4096, xbT, pxT);
      gemm256<1><<<dim3(32, 2, 1), 512, 0, stream>>>(xbT, 0, 1024, WtB, 0, 1024,
                                                     thetaT, 0, 512, 1024,
                                                     bt, nullptr, 0, SCALE, nullptr);
      gemm256<1><<<dim3(8, 2, 1), 512, 0, stream>>>(pxT, 0, 1024, WpB, 0, 1024,
                                                    phiT, 0, 512, 1024,
                                                    bp, nullptr, 0, 1.f, nullptr);
      gemm256<2><<<dim3(4, 4, 1), 512, 0, stream>>>(WgB, 0, 1024, pxT, 0, 1024,
                                                    g, 0, 1024, 1024,
                                                    bg, nullptr, 0, 1.f, nullptr);
      zero_k<<<16, 256, 0, stream>>>(rsum, 4096);
      gemm256<5><<<dim3(32, 4, 1), 512, 0, stream>>>(thetaT, 0, 512, phiT, 0, 512,
                                                     Pt, 0, 1024, 512,
                                                     nullptr, nullptr, 0, 1.f, rsum);
      gemm256<7><<<dim3(32, 2, 1), 512, 0, stream>>>(Pt, 0, 1024, g, 0, 1024,
                                                     tT, 0, 512, 1024,
                                                     rsum, nullptr, 0, 1.f, nullptr);
      gemm256<4><<<dim3(8, 16, 1), 512, 0, stream>>>(WoB, 0, 512, tT, 0, 512,
                                                     out + (size_t)b * 1024 * 4096,
                                                     1024ll * 4096, 4096, 512,
                                                     bo, x + (size_t)b * 1024 * 4096,
                                                     1024ll * 4096, 1.f, nullptr);
    }
  }
}

// Round 16
// 305.746 us; speedup vs baseline: 1.0578x; 1.0495x over previous
//
#include <hip/hip_runtime.h>
#include <hip/hip_bf16.h>
#include <stdint.h>

typedef __bf16 bf16;
typedef __bf16 bf16x8 __attribute__((ext_vector_type(8)));
typedef __bf16 bf16x4 __attribute__((ext_vector_type(4)));
typedef float f32x4 __attribute__((ext_vector_type(4)));

#define GLOAD_LDS16(gptr, lptr)                                                        \
  __builtin_amdgcn_global_load_lds((const __attribute__((address_space(1))) void*)(gptr), \
                                   (__attribute__((address_space(3))) void*)(lptr), 16, 0, 0)

// ---------------- weight cast fp32 -> bf16 ----------------
__global__ __launch_bounds__(256) void cast_f2b(const float* __restrict__ in,
                                                bf16* __restrict__ out, int n) {
  int i = (blockIdx.x * 256 + threadIdx.x) * 4;
  if (i >= n) return;
  const float4 v = *(const float4*)(in + i);
  bf16x4 o;
  o[0] = (bf16)v.x; o[1] = (bf16)v.y; o[2] = (bf16)v.z; o[3] = (bf16)v.w;
  *(bf16x4*)(out + i) = o;
}

__global__ __launch_bounds__(256) void zero_k(float* __restrict__ p, int n) {
  int i = blockIdx.x * 256 + threadIdx.x;
  if (i < n) p[i] = 0.f;
}

// concat [bp(512); bg(512)] -> o[1024]
__global__ __launch_bounds__(256) void concat512(const float* __restrict__ a,
                                                 const float* __restrict__ b,
                                                 float* __restrict__ o) {
  int i = blockIdx.x * 256 + threadIdx.x;
  if (i < 512) o[i] = a[i];
  else if (i < 1024) o[i] = b[i - 512];
}

// ---------------- prep v2: cast+transpose x -> xbT[n][c], 2x2 maxpool -> pxT[m][c]
__global__ __launch_bounds__(256) void prep_kernel(const float* __restrict__ x,
                                                   bf16* __restrict__ xbT,
                                                   bf16* __restrict__ pxT) {
  const int b = blockIdx.y;
  x   += (size_t)b * 1024 * 4096;
  xbT += (size_t)b * 4096 * 1024;
  pxT += (size_t)b * 1024 * 1024;
  const int bid = blockIdx.x;
  const int h0 = bid & 31, ct = bid >> 5;
  const int tid = threadIdx.x;
  __shared__ float tile[64][129];
  const float* xs = x + (size_t)(ct * 64) * 4096 + h0 * 128;
#pragma unroll
  for (int e = 0; e < 8; ++e) {
    const int idx = e * 256 + tid;
    const int c = idx >> 5, n4 = (idx & 31) * 4;
    *(float4*)&tile[c][n4] = *(const float4*)&xs[(size_t)c * 4096 + n4];
  }
  __syncthreads();
  bf16* xo = xbT + (size_t)(h0 * 128) * 1024 + ct * 64;
#pragma unroll
  for (int e = 0; e < 4; ++e) {
    const int flat = e * 256 + tid;
    const int n = flat >> 3, c8 = (flat & 7) * 8;
    bf16x8 o;
#pragma unroll
    for (int j = 0; j < 8; ++j) o[j] = (bf16)tile[c8 + j][n];
    *(bf16x8*)&xo[(size_t)n * 1024 + c8] = o;
  }
  bf16* po = pxT + (size_t)(h0 * 32) * 1024 + ct * 64;
  {
    const int m = tid >> 3, c8 = (tid & 7) * 8;
    bf16x8 o;
#pragma unroll
    for (int j = 0; j < 8; ++j) {
      const int c = c8 + j;
      float v = fmaxf(fmaxf(tile[c][2 * m], tile[c][2 * m + 1]),
                      fmaxf(tile[c][64 + 2 * m], tile[c][64 + 2 * m + 1]));
      o[j] = (bf16)v;
    }
    *(bf16x8*)&po[(size_t)m * 1024 + c8] = o;
  }
}

// ======== 128x256-tile GEMM: C[MxN] = A[MxK] * B[NxK]^T  (R9 schedule) ========
// 1D grid, XCD-chunked bijective swizzle (R11's proven form): blocks sharing a
// B-panel (consecutive bx) land on one XCD's L2 -> panel fetched ~once per XCD
// instead of 8x. All launches have nwg % 8 == 0.
// EPI: 0 plain bf16 ; 1 bf16 (acc+bias[col])*scale ; 2 bf16 acc+bias[row] ;
//      4 fp32 acc+bias[row]+resid ; 5 bf16 exp(acc) + atomic row-sums rs_out ;
//      7 bf16 acc/bias[z*4096+row] ;
//      8 fp32 acc/rs_out[z*4096+col] + bias[row] + resid   [fused PV+out]
template <int EPI>
__global__ __launch_bounds__(512, 4) void gemm256(
    const bf16* __restrict__ A, long long sA, int lda,
    const bf16* __restrict__ B, long long sB, int ldb,
    void* __restrict__ Cv, long long sC, int ldc, int K,
    const float* __restrict__ bias,
    const float* __restrict__ resid, long long sResid, float scale,
    float* __restrict__ rs_out, int gx, int gy) {
  // ---- XCD-chunked bijective swizzle (nwg % 8 == 0 for all launches) ----
  const int nwg = gridDim.x;
  const int flat = blockIdx.x;
  const int swz = (flat & 7) * (nwg >> 3) + (flat >> 3);
  const int bx = swz % gx;
  const int tmp = swz / gx;
  const int by = tmp % gy;
  const int z = tmp / gy;

  A += (size_t)z * sA;
  B += (size_t)z * sB;
  const int tid = threadIdx.x;
  const int w = tid >> 6, lane = tid & 63;
  const int r16 = lane & 15, q4 = lane >> 4;
  const int wm = w >> 2, wn = w & 3;
  const long long tileM = (long long)bx * 128;
  const long long tileN = (long long)by * 256;

  __shared__ bf16 As[2][4096];
  __shared__ bf16 Bs[2][8192];

  f32x4 acc[4][4] = {};

  const int srow = tid >> 2;
  const int skb  = (tid & 3) ^ ((srow >> 1) & 3);   // inverse swizzle on source
  const char* Ag = (const char*)A + ((size_t)(tileM + srow) * lda + skb * 8) * 2;
  const char* Bg = (const char*)B + ((size_t)(tileN + srow) * ldb + skb * 8) * 2;
  const size_t b128 = (size_t)128 * ldb * 2;

  auto stage = [&](int T) {
    const int sl = T & 1;
    GLOAD_LDS16(Ag + (size_t)T * 64, &As[sl][w * 512]);
    GLOAD_LDS16(Bg + (size_t)T * 64, &Bs[sl][w * 512]);
    GLOAD_LDS16(Bg + (size_t)T * 64 + b128, &Bs[sl][4096 + w * 512]);
  };

  stage(0);
  const int NT = K >> 5;

  for (int T = 0; T < NT; ++T) {
    asm volatile("s_waitcnt vmcnt(0)" ::: "memory");
    __builtin_amdgcn_s_barrier();
    asm volatile("" ::: "memory");
    if (T + 1 < NT) stage(T + 1);

    const char* Asl = (const char*)&As[T & 1][0];
    const char* Bsl = (const char*)&Bs[T & 1][0];
    bf16x8 af[4], bf_[4];
#pragma unroll
    for (int mi = 0; mi < 4; ++mi) {
      const int row = wm * 64 + mi * 16 + r16;
      af[mi] = *(const bf16x8*)(Asl + row * 64 + ((q4 ^ ((row >> 1) & 3)) << 4));
    }
#pragma unroll
    for (int ni = 0; ni < 4; ++ni) {
      const int row = wn * 64 + ni * 16 + r16;
      bf_[ni] = *(const bf16x8*)(Bsl + row * 64 + ((q4 ^ ((row >> 1) & 3)) << 4));
    }
    __builtin_amdgcn_s_setprio(1);
#pragma unroll
    for (int mi = 0; mi < 4; ++mi)
#pragma unroll
      for (int ni = 0; ni < 4; ++ni)
        acc[mi][ni] = __builtin_amdgcn_mfma_f32_16x16x32_bf16(af[mi], bf_[ni], acc[mi][ni], 0, 0, 0);
    __builtin_amdgcn_s_setprio(0);
  }

  if constexpr (EPI == 4) {
    float* C = (float*)Cv + (size_t)z * sC;
    const float* rz = resid + (size_t)z * sResid;
#pragma unroll
    for (int a = 0; a < 4; ++a) {
      const int row0 = (int)tileM + wm * 64 + a * 16 + q4 * 4;
#pragma unroll
      for (int ni = 0; ni < 4; ++ni) {
        const int col = (int)tileN + wn * 64 + ni * 16 + r16;
#pragma unroll
        for (int r = 0; r < 4; ++r)
          C[(size_t)(row0 + r) * ldc + col] =
              acc[a][ni][r] + bias[row0 + r] + rz[(size_t)(row0 + r) * ldc + col];
      }
    }
  } else if constexpr (EPI == 8) {
    float* C = (float*)Cv + (size_t)z * sC;
    const float* rz = resid + (size_t)z * sResid;
    const float* rsp = rs_out + (size_t)z * 4096;
#pragma unroll
    for (int a = 0; a < 4; ++a) {
      const int row0 = (int)tileM + wm * 64 + a * 16 + q4 * 4;
      float bv[4];
#pragma unroll
      for (int r = 0; r < 4; ++r) bv[r] = bias[row0 + r];
#pragma unroll
      for (int ni = 0; ni < 4; ++ni) {
        const int col = (int)tileN + wn * 64 + ni * 16 + r16;
        const float cinv = 1.0f / rsp[col];
#pragma unroll
        for (int r = 0; r < 4; ++r)
          C[(size_t)(row0 + r) * ldc + col] =
              acc[a][ni][r] * cinv + bv[r] + rz[(size_t)(row0 + r) * ldc + col];
      }
    }
  } else if constexpr (EPI == 5) {
    bf16* C = (bf16*)Cv + (size_t)z * sC;
    float* rsp = rs_out + (size_t)z * 4096;
#pragma unroll
    for (int a = 0; a < 4; ++a) {
      const int row0 = (int)tileM + wm * 64 + a * 16 + q4 * 4;
      float psum[4] = {0.f, 0.f, 0.f, 0.f};
#pragma unroll
      for (int ni = 0; ni < 4; ++ni) {
        const int col = (int)tileN + wn * 64 + ni * 16 + r16;
#pragma unroll
        for (int r = 0; r < 4; ++r) {
          float e = __expf(acc[a][ni][r]);
          psum[r] += e;
          C[(size_t)(row0 + r) * ldc + col] = (bf16)e;
        }
      }
#pragma unroll
      for (int r = 0; r < 4; ++r) {
        float v = psum[r];
        v += __shfl_xor(v, 1);
        v += __shfl_xor(v, 2);
        v += __shfl_xor(v, 4);
        v += __shfl_xor(v, 8);
        if (r16 == 0) atomicAdd(&rsp[row0 + r], v);
      }
    }
  } else if constexpr (EPI == 7) {
    bf16* C = (bf16*)Cv + (size_t)z * sC;
    const float* rsp = bias + (size_t)z * 4096;
#pragma unroll
    for (int a = 0; a < 4; ++a) {
      const int row0 = (int)tileM + wm * 64 + a * 16 + q4 * 4;
      float inv[4];
#pragma unroll
      for (int r = 0; r < 4; ++r) inv[r] = 1.0f / rsp[row0 + r];
#pragma unroll
      for (int ni = 0; ni < 4; ++ni) {
        const int col = (int)tileN + wn * 64 + ni * 16 + r16;
#pragma unroll
        for (int r = 0; r < 4; ++r)
          C[(size_t)(row0 + r) * ldc + col] = (bf16)(acc[a][ni][r] * inv[r]);
      }
    }
  } else if constexpr (EPI == 2) {
    bf16* C = (bf16*)Cv + (size_t)z * sC;
#pragma unroll
    for (int a = 0; a < 4; ++a) {
      const int row0 = (int)tileM + wm * 64 + a * 16 + q4 * 4;
#pragma unroll
      for (int ni = 0; ni < 4; ++ni) {
        const int col = (int)tileN + wn * 64 + ni * 16 + r16;
#pragma unroll
        for (int r = 0; r < 4; ++r)
          C[(size_t)(row0 + r) * ldc + col] = (bf16)(acc[a][ni][r] + bias[row0 + r]);
      }
    }
  } else if constexpr (EPI == 0) {
    bf16* C = (bf16*)Cv + (size_t)z * sC;
#pragma unroll
    for (int a = 0; a < 4; ++a) {
      const int row0 = (int)tileM + wm * 64 + a * 16 + q4 * 4;
#pragma unroll
      for (int ni = 0; ni < 4; ++ni) {
        const int col = (int)tileN + wn * 64 + ni * 16 + r16;
#pragma unroll
        for (int r = 0; r < 4; ++r)
          C[(size_t)(row0 + r) * ldc + col] = (bf16)acc[a][ni][r];
      }
    }
  } else {  // EPI == 1
    bf16* C = (bf16*)Cv + (size_t)z * sC;
#pragma unroll
    for (int a = 0; a < 4; ++a) {
      const int row0 = (int)tileM + wm * 64 + a * 16 + q4 * 4;
#pragma unroll
      for (int ni = 0; ni < 4; ++ni) {
        const int col = (int)tileN + wn * 64 + ni * 16 + r16;
        const float badd = bias[col];
#pragma unroll
        for (int r = 0; r < 4; ++r)
          C[(size_t)(row0 + r) * ldc + col] = (bf16)((acc[a][ni][r] + badd) * scale);
      }
    }
  }
}

// ---------------- launch ----------------
extern "C" void kernel_launch(void* const* d_in, const int* in_sizes, int n_in,
                              void* d_out, int out_size, void* d_ws, size_t ws_size,
                              hipStream_t stream) {
  const float* x  = (const float*)d_in[0];
  const float* Wt = (const float*)d_in[1];
  const float* bt = (const float*)d_in[2];
  const float* Wp = (const float*)d_in[3];
  const float* bp = (const float*)d_in[4];
  const float* Wg = (const float*)d_in[5];
  const float* bg = (const float*)d_in[6];
  const float* Wo = (const float*)d_in[7];
  const float* bo = (const float*)d_in[8];
  float* out = (float*)d_out;

  const size_t MB = 1024ull * 1024ull;
  char* ws = (char*)d_ws;
  bf16* WtB  = (bf16*)(ws + 0 * MB);            // 1MB
  bf16* WoB  = (bf16*)(ws + 1 * MB);            // 1MB
  bf16* WpgB = (bf16*)(ws + 2 * MB);            // 2MB: rows 0-511 Wp, 512-1023 Wg

  cast_f2b<<<512, 256, 0, stream>>>(Wt, WtB, 512 * 1024);
  cast_f2b<<<512, 256, 0, stream>>>(Wo, WoB, 1024 * 512);
  cast_f2b<<<512, 256, 0, stream>>>(Wp, WpgB, 512 * 1024);
  cast_f2b<<<512, 256, 0, stream>>>(Wg, WpgB + 512 * 1024, 512 * 1024);

  const float SCALE = 0.044194173824159216f;  // 512^-0.5, folded into theta

  // gemm256 launcher: 1D grid (gx*gy*gz blocks) with XCD-chunk swizzle
#define G256(EPI_, gx_, gy_, gz_, A_, sA_, lda_, B_, sB_, ldb_, Cv_, sC_, ldc_, K_, \
             bias_, resid_, sResid_, scale_, rs_)                                    \
  gemm256<EPI_><<<(gx_) * (gy_) * (gz_), 512, 0, stream>>>(                          \
      A_, sA_, lda_, B_, sB_, ldb_, Cv_, sC_, ldc_, K_, bias_, resid_, sResid_,      \
      scale_, rs_, gx_, gy_)

  if (ws_size >= 164 * MB) {
    // ---- fused pipeline: pg = [phi|gT]; W2 = Wo.gT^T; out = (W2.P^T)/rs + b + x
    float* bias_pg = (float*)(ws + 4 * MB);           // 4KB
    float* rsum    = (float*)(ws + 4 * MB + 65536);   // 128KB
    bf16* pxT    = (bf16*)(ws + 5 * MB);              // 16MB
    bf16* pg     = (bf16*)(ws + 21 * MB);             // 16MB [z][m][d2=1024]
    bf16* thetaT = (bf16*)(ws + 37 * MB);             // 32MB
    bf16* W2     = (bf16*)(ws + 69 * MB);             // 16MB [z][o][m]
    bf16* xbT    = (bf16*)(ws + 100 * MB);            // 64MB
    bf16* Pt     = xbT;                               // xbT dead after G1

    concat512<<<4, 256, 0, stream>>>(bp, bg, bias_pg);
    prep_kernel<<<dim3(512, 8), 256, 0, stream>>>(x, xbT, pxT);
    G256(1, 32, 2, 8, xbT, 4096ll * 1024, 1024, WtB, 0, 1024,
         thetaT, 4096ll * 512, 512, 1024, bt, nullptr, 0, SCALE, nullptr);
    G256(1, 8, 4, 8, pxT, 1024ll * 1024, 1024, WpgB, 0, 1024,
         pg, 1024ll * 1024, 1024, 1024, bias_pg, nullptr, 0, 1.f, nullptr);
    G256(0, 8, 4, 8, WoB, 0, 512, pg + 512, 1024ll * 1024, 1024,
         W2, 1024ll * 1024, 1024, 512, nullptr, nullptr, 0, 1.f, nullptr);
    zero_k<<<128, 256, 0, stream>>>(rsum, 32768);
    G256(5, 32, 4, 8, thetaT, 4096ll * 512, 512, pg, 1024ll * 1024, 1024,
         Pt, 4096ll * 1024, 1024, 512, nullptr, nullptr, 0, 1.f, rsum);
    G256(8, 8, 16, 8, W2, 1024ll * 1024, 1024, Pt, 4096ll * 1024, 1024,
         out, 1024ll * 4096, 4096, 1024, bo, x, 1024ll * 4096, 1.f, rsum);
  } else if (ws_size >= 108 * MB) {
    // ---- split pipeline ----
    bf16* WpB = WpgB;
    bf16* WgB = WpgB + 512 * 1024;
    bf16* pxT    = (bf16*)(ws + 4 * MB);
    bf16* phiT   = (bf16*)(ws + 20 * MB);
    bf16* g      = (bf16*)(ws + 28 * MB);
    bf16* thetaT = (bf16*)(ws + 36 * MB);
    bf16* tT     = (bf16*)(ws + 68 * MB);
    bf16* xbT    = (bf16*)(ws + 100 * MB);   // 8MB per-batch staging
    float* rsum = (float*)((char*)d_out + 80 * MB);
    for (int b = 0; b < 8; ++b) {
      prep_kernel<<<dim3(512, 1), 256, 0, stream>>>(x + (size_t)b * 1024 * 4096, xbT,
                                                    pxT + (size_t)b * 1024 * 1024);
      G256(1, 32, 2, 1, xbT, 0, 1024, WtB, 0, 1024,
           thetaT + (size_t)b * 4096 * 512, 0, 512, 1024, bt, nullptr, 0, SCALE, nullptr);
    }
    G256(1, 8, 2, 8, pxT, 1024ll * 1024, 1024, WpB, 0, 1024,
         phiT, 1024ll * 512, 512, 1024, bp, nullptr, 0, 1.f, nullptr);
    G256(2, 4, 4, 8, WgB, 0, 1024, pxT, 1024ll * 1024, 1024,
         g, 512ll * 1024, 1024, 1024, bg, nullptr, 0, 1.f, nullptr);
    for (int b = 0; b < 8; ++b) {
      bf16* Ptb = (bf16*)d_out + (size_t)b * 4096 * 1024;
      zero_k<<<16, 256, 0, stream>>>(rsum + (size_t)b * 4096, 4096);
      G256(5, 32, 4, 1, thetaT + (size_t)b * 4096 * 512, 0, 512,
           phiT + (size_t)b * 1024 * 512, 0, 512,
           Ptb, 0, 1024, 512, nullptr, nullptr, 0, 1.f, rsum + (size_t)b * 4096);
      G256(7, 32, 2, 1, Ptb, 0, 1024, g + (size_t)b * 512 * 1024, 0, 1024,
           tT + (size_t)b * 4096 * 512, 0, 512, 1024,
           rsum + (size_t)b * 4096, nullptr, 0, 1.f, nullptr);
    }
    G256(4, 8, 16, 8, WoB, 0, 512, tT, 4096ll * 512, 512,
         out, 1024ll * 4096, 4096, 512, bo, x, 1024ll * 4096, 1.f, nullptr);
  } else {
    // ---- per-batch minimal-ws pipeline ----
    bf16* WpB = WpgB;
    bf16* WgB = WpgB + 512 * 1024;
    float* rsum  = (float*)(ws + 4 * MB);    // 16KB
    bf16* pxT    = (bf16*)(ws + 5 * MB);     // 2MB
    bf16* phiT   = (bf16*)(ws + 7 * MB);     // 1MB
    bf16* g      = (bf16*)(ws + 8 * MB);     // 1MB
    bf16* thetaT = (bf16*)(ws + 9 * MB);     // 4MB
    bf16* tT     = (bf16*)(ws + 13 * MB);    // 4MB
    bf16* Pt     = (bf16*)(ws + 17 * MB);    // 8MB
    bf16* xbT    = (bf16*)(ws + 25 * MB);    // 8MB
    for (int b = 0; b < 8; ++b) {
      prep_kernel<<<dim3(512, 1), 256, 0, stream>>>(x + (size_t)b * 1024 * 4096, xbT, pxT);
      G256(1, 32, 2, 1, xbT, 0, 1024, WtB, 0, 1024,
           thetaT, 0, 512, 1024, bt, nullptr, 0, SCALE, nullptr);
      G256(1, 8, 2, 1, pxT, 0, 1024, WpB, 0, 1024,
           phiT, 0, 512, 1024, bp, nullptr, 0, 1.f, nullptr);
      G256(2, 4, 4, 1, WgB, 0, 1024, pxT, 0, 1024,
           g, 0, 1024, 1024, bg, nullptr, 0, 1.f, nullptr);
      zero_k<<<16, 256, 0, stream>>>(rsum, 4096);
      G256(5, 32, 4, 1, thetaT, 0, 512, phiT, 0, 512,
           Pt, 0, 1024, 512, nullptr, nullptr, 0, 1.f, rsum);
      G256(7, 32, 2, 1, Pt, 0, 1024, g, 0, 1024,
           tT, 0, 512, 1024, rsum, nullptr, 0, 1.f, nullptr);
      G256(4, 8, 16, 1, WoB, 0, 512, tT, 0, 512,
           out + (size_t)b * 1024 * 4096, 1024ll * 4096, 4096, 512,
           bo, x + (size_t)b * 1024 * 4096, 1024ll * 4096, 1.f, nullptr);
    }
  }
#undef G256
}